// Round 4
// baseline (171.536 us; speedup 1.0000x reference)
//
#include <hip/hip_runtime.h>
#include <cmath>

#define NA 8400
#define NC 80
#define BS 16
#define NMAX 64
#define TOPKK 13
#define MAXCELL 768
#define CEPS 1e-9f
#define PIF 3.14159265358979323846f

// d_out layout (float32, concatenated)
#define OFF_LABELS  0
#define OFF_CIRCLES 134400
#define OFF_SCORES  537600
#define OFF_FG      11289600
#define OFF_TGI     11424000

// workspace layout (bytes)
#define WS_POSAL   1075200
#define WS_POSOV   1079296
#define WS_TGI     1083392
#define WS_ALIGN   1620992
#define ZERO1_F4   67712      // (colbits+posal+posov)/16
#define NSC_F4     2688000    // target_scores floats/4

__device__ __forceinline__ float circle_iou_dev(float gx, float gy, float r1,
                                                float px, float py, float r2) {
    float dx = gx - px, dy = gy - py;
    float d = sqrtf(dx * dx + dy * dy + CEPS);
    float a1 = PIF * r1 * r1, a2 = PIF * r2 * r2;
    float d2 = d * d;
    float c1 = (d2 + r1 * r1 - r2 * r2) / (2.0f * d * r1 + CEPS);
    float c2 = (d2 + r2 * r2 - r1 * r1) / (2.0f * d * r2 + CEPS);
    c1 = fminf(fmaxf(c1, -1.0f), 1.0f);
    c2 = fminf(fmaxf(c2, -1.0f), 1.0f);
    float tri = fmaxf((r1 + r2 - d) * (d + r1 - r2) * (d - r1 + r2) * (d + r1 + r2), 0.0f);
    float lens = r1 * r1 * acosf(c1) + r2 * r2 * acosf(c2) - 0.5f * sqrtf(tri);
    float inter;
    if (d >= r1 + r2)             inter = 0.0f;
    else if (d <= fabsf(r1 - r2)) { float rm = fminf(r1, r2); inter = PIF * rm * rm; }
    else                          inter = lens;
    return inter / (a1 + a2 - inter + CEPS);
}

// K0: zero colbits + posal + posov (1.08 MB)
__global__ __launch_bounds__(256) void k0_zero(float4* __restrict__ wsz)
{
    int i = blockIdx.x * 256 + threadIdx.x;
    if (i < ZERO1_F4) wsz[i] = make_float4(0.f, 0.f, 0.f, 0.f);
}

// K1: one block per (b, j). DETERMINISTIC bbox-cell -> LDS slot mapping
// (no atomic compaction: cell i is always slot i, processed by thread i&255,
// so align values are bit-identical across runs). Cell order is strictly
// increasing in anchor index => tie-break by min cell == min anchor.
__global__ __launch_bounds__(256) void k1_topk(
    const float* __restrict__ pd_scores, const float* __restrict__ pd_circles,
    const int* __restrict__ gt_labels, const float* __restrict__ gt_bboxes,
    const float* __restrict__ mask_gt, unsigned long long* __restrict__ colbits)
{
    __shared__ float s_val[MAXCELL];
    __shared__ float s_low[64];
    __shared__ unsigned long long s_ingt0;
    __shared__ int   s_nsel, s_done;
    __shared__ float s_redv[4];
    __shared__ int   s_redi[4];
    __shared__ int   s_sel[16];

    const int row = blockIdx.x;            // b*64 + j
    const int b = row >> 6, j = row & 63;
    const int t = threadIdx.x;
    const int lane = t & 63, wv = t >> 6;

    if (mask_gt[row] <= 0.0f) return;      // colbits pre-zeroed by K0

    const float gx = gt_bboxes[row * 3 + 0];
    const float gy = gt_bboxes[row * 3 + 1];
    const float gr = gt_bboxes[row * 3 + 2];
    int lab = gt_labels[row];
    lab = min(max(lab, 0), NC - 1);

    if (t == 0) { s_nsel = 0; s_done = 0; }
    if (t < 64) s_low[t] = 0.0f;

    // bbox ranges per level (1-cell margin; exact in-circle test authoritative)
    int c0_0, r0_0, w_0, c0_1, r0_1, w_1, c0_2, r0_2, w_2;
    int off1, off2, tot;
    {
        float inv = 0.125f;
        c0_0 = max(0, (int)floorf((gx - gr) * inv - 0.5f) - 1);
        int c1 = min(79, (int)ceilf((gx + gr) * inv - 0.5f) + 1);
        r0_0 = max(0, (int)floorf((gy - gr) * inv - 0.5f) - 1);
        int r1 = min(79, (int)ceilf((gy + gr) * inv - 0.5f) + 1);
        w_0 = max(0, c1 - c0_0 + 1); int h0 = max(0, r1 - r0_0 + 1);
        inv = 0.0625f;
        c0_1 = max(0, (int)floorf((gx - gr) * inv - 0.5f) - 1);
        c1 = min(39, (int)ceilf((gx + gr) * inv - 0.5f) + 1);
        r0_1 = max(0, (int)floorf((gy - gr) * inv - 0.5f) - 1);
        r1 = min(39, (int)ceilf((gy + gr) * inv - 0.5f) + 1);
        w_1 = max(0, c1 - c0_1 + 1); int h1 = max(0, r1 - r0_1 + 1);
        inv = 0.03125f;
        c0_2 = max(0, (int)floorf((gx - gr) * inv - 0.5f) - 1);
        c1 = min(19, (int)ceilf((gx + gr) * inv - 0.5f) + 1);
        r0_2 = max(0, (int)floorf((gy - gr) * inv - 0.5f) - 1);
        r1 = min(19, (int)ceilf((gy + gr) * inv - 0.5f) + 1);
        w_2 = max(0, c1 - c0_2 + 1); int h2 = max(0, r1 - r0_2 + 1);
        off1 = w_0 * h0;
        off2 = off1 + w_1 * h1;
        tot  = min(off2 + w_2 * h2, MAXCELL);   // bound: <=734 for r<=72
    }

    // in-gt bits for anchors 0..63 (level 0, row 0, cols 0..63)
    if (wv == 0) {
        float ax = ((float)lane + 0.5f) * 8.0f;
        float dx = gx - ax, dy = gy - 4.0f;
        bool ig = (sqrtf(dx * dx + dy * dy) <= gr);
        unsigned long long m = __ballot(ig);
        if (lane == 0) s_ingt0 = m;
    }
    __syncthreads();

    // fused phase A+B: fixed cell->slot mapping, align computed in place
    for (int i = t; i < tot; i += 256) {
        int rr, cc, base, nlev; float s;
        if (i < off1)      { int l = i;        rr = r0_0 + l / w_0; cc = c0_0 + l % w_0; base = 0;    nlev = 80; s = 8.0f;  }
        else if (i < off2) { int l = i - off1; rr = r0_1 + l / w_1; cc = c0_1 + l % w_1; base = 6400; nlev = 40; s = 16.0f; }
        else               { int l = i - off2; rr = r0_2 + l / w_2; cc = c0_2 + l % w_2; base = 8000; nlev = 20; s = 32.0f; }
        float ax = ((float)cc + 0.5f) * s;
        float ay = ((float)rr + 0.5f) * s;
        float dx = gx - ax, dy = gy - ay;
        float v = 0.0f;
        int a = base + rr * nlev + cc;
        if (sqrtf(dx * dx + dy * dy) <= gr) {
            size_t pi = (size_t)(b * NA + a);
            float px = pd_circles[pi * 3 + 0];
            float py = pd_circles[pi * 3 + 1];
            float pr = pd_circles[pi * 3 + 2];
            float iou = circle_iou_dev(gx, gy, gr, px, py, pr);
            float sc  = pd_scores[pi * NC + lab];
            float o2 = iou * iou;
            v = sc * (o2 * o2 * o2);
        }
        s_val[i] = v;
        if (a < 64) s_low[a] = v;
    }
    __syncthreads();

    // phase C: 13-pass argmax over cells (value desc, cell idx asc == anchor asc)
    for (int it = 0; it < TOPKK; ++it) {
        float bv = -1.0f; int bi = 1 << 30;
        for (int i = t; i < tot; i += 256) {
            float v = s_val[i];
            if (v > bv || (v == bv && i < bi)) { bv = v; bi = i; }
        }
        for (int off = 32; off > 0; off >>= 1) {
            float ov = __shfl_down(bv, off);
            int   oi = __shfl_down(bi, off);
            if (ov > bv || (ov == bv && oi < bi)) { bv = ov; bi = oi; }
        }
        if (lane == 0) { s_redv[wv] = bv; s_redi[wv] = bi; }
        __syncthreads();
        if (t == 0) {
            float vb = s_redv[0]; int ib = s_redi[0];
            for (int w = 1; w < 4; ++w)
                if (s_redv[w] > vb || (s_redv[w] == vb && s_redi[w] < ib))
                    { vb = s_redv[w]; ib = s_redi[w]; }
            if (vb > 0.0f) {
                int rr, cc, base, nlev;
                if (ib < off1)      { int l = ib;        rr = r0_0 + l / w_0; cc = c0_0 + l % w_0; base = 0;    nlev = 80; }
                else if (ib < off2) { int l = ib - off1; rr = r0_1 + l / w_1; cc = c0_1 + l % w_1; base = 6400; nlev = 40; }
                else                { int l = ib - off2; rr = r0_2 + l / w_2; cc = c0_2 + l % w_2; base = 8000; nlev = 20; }
                s_sel[s_nsel] = base + rr * nlev + cc;
                s_nsel++;
                s_val[ib] = -1.0f;
            } else s_done = 1;
        }
        __syncthreads();
        if (s_done) break;
    }

    // phase D: zero-filler — top_k fills remaining slots with globally
    // lowest-index zero-valued anchors (always within 0..63); keep in-gt ones.
    if (t == 0) {
        int r = TOPKK - s_nsel;
        if (r > 0) {
            for (int idx = 0; idx < 64 && r > 0; ++idx) {
                if (s_low[idx] > 0.0f) continue;
                r--;
                if ((s_ingt0 >> idx) & 1ull) { s_sel[s_nsel] = idx; s_nsel++; }
            }
        }
    }
    __syncthreads();

    // phase E: set bit j in each selected anchor's GT column
    if (t < s_nsel)
        atomicOr(&colbits[(size_t)b * NA + s_sel[t]], 1ull << j);
}

// K2: one thread per (b, a). Coalesced column read; resolve contested anchors
// by overlap argmax (first-max); outputs + pos arrays via atomicMax.
__global__ __launch_bounds__(256) void k2_resolve(
    const float* __restrict__ pd_scores, const float* __restrict__ pd_circles,
    const float* __restrict__ anc, const int* __restrict__ gt_labels,
    const float* __restrict__ gt_bboxes, const float* __restrict__ mask_gt,
    const unsigned long long* __restrict__ colbits,
    float* __restrict__ out, int* __restrict__ tgiE, float* __restrict__ alignv,
    unsigned int* __restrict__ posal, unsigned int* __restrict__ posov)
{
    const int idx = blockIdx.x * 256 + threadIdx.x;   // < 134400
    const int b = idx / NA;
    const int a = idx - b * NA;

    const unsigned long long col = colbits[idx];
    const int cnt = __popcll(col);

    int tgi = 0, fg = 0;
    if (cnt == 1) { fg = 1; tgi = __ffsll((unsigned long long)col) - 1; }
    else if (cnt > 1) {
        fg = 1;
        float px = pd_circles[(size_t)idx * 3 + 0];
        float py = pd_circles[(size_t)idx * 3 + 1];
        float pr = pd_circles[(size_t)idx * 3 + 2];
        float ax = anc[2 * a], ay = anc[2 * a + 1];
        float bo = -1.0f; int bj = 0;
        for (int j = 0; j < NMAX; ++j) {
            float mgv = mask_gt[b * NMAX + j];
            float gx = gt_bboxes[(b * NMAX + j) * 3 + 0];
            float gy = gt_bboxes[(b * NMAX + j) * 3 + 1];
            float gr = gt_bboxes[(b * NMAX + j) * 3 + 2];
            float ovj = 0.0f;
            if (mgv > 0.0f) {
                float dx = gx - ax, dy = gy - ay;
                if (sqrtf(dx * dx + dy * dy) <= gr)
                    ovj = circle_iou_dev(gx, gy, gr, px, py, pr);
            }
            if (ovj > bo) { bo = ovj; bj = j; }  // strict >: first-max
        }
        tgi = bj;
    }

    const int gl = gt_labels[b * NMAX + tgi];
    const float gx = gt_bboxes[(b * NMAX + tgi) * 3 + 0];
    const float gy = gt_bboxes[(b * NMAX + tgi) * 3 + 1];
    const float gr = gt_bboxes[(b * NMAX + tgi) * 3 + 2];

    out[OFF_LABELS + idx] = (float)max(gl, 0);
    out[OFF_CIRCLES + (size_t)idx * 3 + 0] = gx;
    out[OFF_CIRCLES + (size_t)idx * 3 + 1] = gy;
    out[OFF_CIRCLES + (size_t)idx * 3 + 2] = gr;
    out[OFF_FG + idx]  = (float)fg;
    out[OFF_TGI + idx] = (float)tgi;
    tgiE[idx] = fg ? tgi : -1;

    float alg = 0.0f;
    if (fg) {
        float ovv = 0.0f;
        float mgv = mask_gt[b * NMAX + tgi];
        float ax = anc[2 * a], ay = anc[2 * a + 1];
        float dx = gx - ax, dy = gy - ay;
        if (mgv > 0.0f && sqrtf(dx * dx + dy * dy) <= gr) {
            float px = pd_circles[(size_t)idx * 3 + 0];
            float py = pd_circles[(size_t)idx * 3 + 1];
            float pr = pd_circles[(size_t)idx * 3 + 2];
            float iou = circle_iou_dev(gx, gy, gr, px, py, pr);
            int lab = min(max(gl, 0), NC - 1);
            float sc = pd_scores[((size_t)b * NA + a) * NC + lab];
            ovv = iou;
            float o2 = iou * iou;
            alg = sc * (o2 * o2 * o2);
        }
        atomicMax(&posal[b * NMAX + tgi], __float_as_uint(alg));
        atomicMax(&posov[b * NMAX + tgi], __float_as_uint(ovv));
    }
    alignv[idx] = alg;
}

// K3: write target_scores in ONE pass — zeros everywhere, norm at (anchor,label)
__global__ __launch_bounds__(256) void k3_scores(
    const int* __restrict__ tgiE, const float* __restrict__ alignv,
    const unsigned int* __restrict__ posal, const unsigned int* __restrict__ posov,
    const int* __restrict__ gt_labels, float4* __restrict__ scores)
{
    const int i = blockIdx.x * 256 + threadIdx.x;     // < 2,688,000 (exact grid)
    const int anchor = i / 20;                        // 20 float4 per anchor
    const int q = i - anchor * 20;                    // classes 4q..4q+3
    float4 v = make_float4(0.f, 0.f, 0.f, 0.f);
    const int tg = tgiE[anchor];
    if (tg >= 0) {
        const int b = anchor / NA;
        const int lab = max(gt_labels[b * NMAX + tg], 0);
        if ((lab >> 2) == q) {
            float pa = __uint_as_float(posal[b * NMAX + tg]);
            float po = __uint_as_float(posov[b * NMAX + tg]);
            float norm = alignv[anchor] * po / (pa + CEPS);
            ((float*)&v)[lab & 3] = norm;
        }
    }
    scores[i] = v;
}

extern "C" void kernel_launch(void* const* d_in, const int* in_sizes, int n_in,
                              void* d_out, int out_size, void* d_ws, size_t ws_size,
                              hipStream_t stream) {
    const float* pd_scores  = (const float*)d_in[0];
    const float* pd_circles = (const float*)d_in[1];
    const float* anc        = (const float*)d_in[2];
    const int*   gt_labels  = (const int*)d_in[3];
    const float* gt_bboxes  = (const float*)d_in[4];
    const float* mask_gt    = (const float*)d_in[5];
    float* out = (float*)d_out;

    char* ws = (char*)d_ws;
    unsigned long long* colbits = (unsigned long long*)ws;
    unsigned int* posal = (unsigned int*)(ws + WS_POSAL);
    unsigned int* posov = (unsigned int*)(ws + WS_POSOV);
    int*   tgiE   = (int*)(ws + WS_TGI);
    float* alignv = (float*)(ws + WS_ALIGN);

    k0_zero<<<(ZERO1_F4 + 255) / 256, 256, 0, stream>>>((float4*)ws);
    k1_topk<<<BS * NMAX, 256, 0, stream>>>(pd_scores, pd_circles, gt_labels,
                                           gt_bboxes, mask_gt, colbits);
    k2_resolve<<<(BS * NA) / 256, 256, 0, stream>>>(pd_scores, pd_circles, anc,
                                                    gt_labels, gt_bboxes, mask_gt,
                                                    colbits, out, tgiE, alignv,
                                                    posal, posov);
    k3_scores<<<NSC_F4 / 256, 256, 0, stream>>>(tgiE, alignv, posal, posov,
                                                gt_labels,
                                                (float4*)(out + OFF_SCORES));
}